// Round 1
// 411.182 us; speedup vs baseline: 1.0216x; 1.0216x over previous
//
#include <hip/hip_runtime.h>
#include <cstdint>
#include <cstddef>

#define B_  32
#define L_  4096
#define FT_ 512
#define FS_ 512
#define H_  512
#define C_  1025   // FT + FS + 1
#define TL  32
#define NCH (L_ / TL)   // 128 l-chunks per batch row

typedef __attribute__((ext_vector_type(8))) short short8;   // 8 bf16 = 4 VGPRs
typedef __attribute__((ext_vector_type(4))) float float4v;  // MFMA C/D

// fp32 -> bf16 round-to-nearest-even
__device__ __forceinline__ short f2bf(float f) {
    union { float f; unsigned u; } v; v.f = f;
    unsigned r = v.u + 0x7FFF + ((v.u >> 16) & 1);
    return (short)(r >> 16);
}

// tanh(x) = 1 - 2/(e^2x + 1); graceful at +-inf (->+-1), cheap: exp + rcp.
__device__ __forceinline__ float fast_tanh(float x) {
    float e = __expf(2.f * x);
    return 1.f - 2.f * __builtin_amdgcn_rcpf(e + 1.f);
}

// ---------------------------------------------------------------------------
// Kernel 1 (fused prep): blocks [0,128) pack W1's text block into MFMA
// B-fragment order (bf16) + extract w1c; blocks [128, 128+4096) compute
// sconst[b][h] = b1[h] + W1[h, FT:FT+FS] . summary[b]  (one wave per (b,h)).
//   fragB[((t*16 + s)*64 + lane)*8 + j] = bf16(W1[t*16 + (lane&15)]
//                                              [s*32 + (lane>>4)*8 + j])
// ---------------------------------------------------------------------------
__global__ __launch_bounds__(256) void prep_kernel(
        const float* __restrict__ W1, const float* __restrict__ summary,
        const float* __restrict__ b1, short* __restrict__ fragB,
        float* __restrict__ w1c, float* __restrict__ sconst) {
    if (blockIdx.x < 128) {
        int gid = blockIdx.x * 256 + threadIdx.x;   // granule id, 32768 total
        int lane = gid & 63;
        int ts_  = gid >> 6;        // t*16 + s
        int t = ts_ >> 4;
        int s = ts_ & 15;
        int h  = t * 16 + (lane & 15);
        int k0 = s * 32 + (lane >> 4) * 8;
        const float* src = W1 + (size_t)h * C_ + k0;
        short8 o;
        #pragma unroll
        for (int j = 0; j < 8; ++j) o[j] = f2bf(src[j]);
        *(short8*)(fragB + (size_t)gid * 8) = o;
        if (gid < H_) w1c[gid] = W1[(size_t)gid * C_ + FT_ + FS_];
    } else {
        int wid  = ((blockIdx.x - 128) * 256 + threadIdx.x) >> 6;
        int lane = threadIdx.x & 63;
        int b = wid >> 9;
        int h = wid & 511;
        const float* wrow = W1 + (size_t)h * C_ + FT_;
        const float* srow = summary + (size_t)b * FS_;
        float acc = 0.f;
        #pragma unroll
        for (int f = lane; f < FS_; f += 64) acc += wrow[f] * srow[f];
        #pragma unroll
        for (int off = 32; off > 0; off >>= 1) acc += __shfl_down(acc, off, 64);
        if (lane == 0) sconst[wid] = acc + b1[h];
    }
}

// ---------------------------------------------------------------------------
// Kernel 2 (MFMA logits + FUSED context partial): per block: 32-l tile, all
// 512 h across 4 waves. A staged once in 32 KB XOR-swizzled LDS; B-frags
// streamed from fragB (L2-resident). Epilogue fuses sconst/coverage/tanh/W2,
// 16-lane shfl reduce, cross-wave LDS reduce -> logits. NEW: chunk-local
// softmax (m_c, s_c) + weights w_l = exp(logit-m_c) in LDS, then all 256
// threads accumulate cpart[b][chunk][f] = sum_l w_l * ts[b,l,f] from GLOBAL
// fp32 (rows are L2-hot from the staging pass -- avoids the second full-HBM
// ts read the old context_kernel paid). Global rescale happens in finalize.
// ---------------------------------------------------------------------------
__global__ __launch_bounds__(256, 4) void logits_ctx_kernel(
        const float* __restrict__ ts, const float* __restrict__ coverage,
        const int* __restrict__ text_length,
        const short* __restrict__ fragB, const float* __restrict__ w1c,
        const float* __restrict__ sconst, const float* __restrict__ W2,
        const float* __restrict__ b2, float* __restrict__ logits,
        float2* __restrict__ stats_c, float* __restrict__ cpart) {
    const int b  = blockIdx.y;
    const int l0 = blockIdx.x * TL;
    const int len = text_length[b];
    if (l0 >= len) return;   // uniform early-out before any barrier

    __shared__ short ts_lds[TL * 512];   // 32 KB, XOR-swizzled

    // ---- stage: 2 float4 -> 1 short8 per iter, granule-swizzled ----
    const float4* src = (const float4*)(ts + ((size_t)b * L_ + l0) * FT_);
    for (int j = threadIdx.x; j < TL * 64; j += 256) {
        int l = j >> 6;
        int g = j & 63;                 // 16B granule within row
        float4 v0 = src[2 * j];
        float4 v1 = src[2 * j + 1];
        short8 p;
        p[0] = f2bf(v0.x); p[1] = f2bf(v0.y); p[2] = f2bf(v0.z); p[3] = f2bf(v0.w);
        p[4] = f2bf(v1.x); p[5] = f2bf(v1.y); p[6] = f2bf(v1.z); p[7] = f2bf(v1.w);
        *(short8*)(ts_lds + l * 512 + ((g ^ (l & 7)) << 3)) = p;
    }
    __syncthreads();

    const int lane = threadIdx.x & 63;
    const int wv   = threadIdx.x >> 6;    // wave 0..3 -> h-chunk [128wv,128wv+128)
    const int col  = lane & 15;
    const int quad = lane >> 4;
    const int swz  = col & 7;             // A-row swizzle key (row m = mt*16+col)

    const short* aBase = ts_lds + col * 512;                  // + mt*16*512
    const short* bBase = fragB + (size_t)(wv * 8) * 16 * 512 + lane * 8;

    float4v acc[8][2];                    // [nt][mt]
    #pragma unroll
    for (int nt = 0; nt < 8; ++nt)
        #pragma unroll
        for (int mt = 0; mt < 2; ++mt)
            acc[nt][mt] = (float4v){0.f, 0.f, 0.f, 0.f};

    #pragma unroll 2
    for (int ks = 0; ks < 16; ++ks) {
        short8 af[2];
        const int ag = ((ks * 4 + quad) ^ swz) << 3;
        #pragma unroll
        for (int mt = 0; mt < 2; ++mt)
            af[mt] = *(const short8*)(aBase + mt * (16 * 512) + ag);
        #pragma unroll
        for (int nt = 0; nt < 8; ++nt) {
            short8 bf = *(const short8*)(bBase + (size_t)(nt * 16 + ks) * 512);
            #pragma unroll
            for (int mt = 0; mt < 2; ++mt)
                acc[nt][mt] = __builtin_amdgcn_mfma_f32_16x16x32_bf16(
                    af[mt], bf, acc[nt][mt], 0, 0, 0);
        }
    }

    // ---- epilogue: tanh-weighted h-reduction ----
    const int h0 = wv * 128;
    const float* sc_b = sconst + (size_t)b * H_;
    float4 cov[2];
    #pragma unroll
    for (int mt = 0; mt < 2; ++mt)
        cov[mt] = *(const float4*)(coverage + (size_t)b * L_ + l0 + mt * 16 + quad * 4);

    float partial[2][4];                  // [mt][r], l = mt*16 + quad*4 + r
    #pragma unroll
    for (int mt = 0; mt < 2; ++mt)
        #pragma unroll
        for (int r = 0; r < 4; ++r) partial[mt][r] = 0.f;

    #pragma unroll
    for (int nt = 0; nt < 8; ++nt) {
        const int h = h0 + nt * 16 + col;
        const float sc = sc_b[h];
        const float wc = w1c[h];
        const float w2 = W2[h];
        #pragma unroll
        for (int mt = 0; mt < 2; ++mt)
            #pragma unroll
            for (int r = 0; r < 4; ++r) {
                float pre = acc[nt][mt][r] + sc + wc * ((const float*)&cov[mt])[r];
                partial[mt][r] += w2 * fast_tanh(pre);
            }
    }

    #pragma unroll
    for (int mt = 0; mt < 2; ++mt)
        #pragma unroll
        for (int r = 0; r < 4; ++r) {
            float v = partial[mt][r];
            v += __shfl_xor(v, 8, 64);
            v += __shfl_xor(v, 4, 64);
            v += __shfl_xor(v, 2, 64);
            v += __shfl_xor(v, 1, 64);
            partial[mt][r] = v;
        }

    __syncthreads();                      // done with ts_lds A-data
    float* red  = (float*)ts_lds;         // 4 waves x 32 l partials (128 f)
    float* wbuf = red + 128;              // 32 chunk-local softmax weights
    if (col == 0) {
        #pragma unroll
        for (int mt = 0; mt < 2; ++mt)
            #pragma unroll
            for (int r = 0; r < 4; ++r)
                red[wv * 32 + mt * 16 + quad * 4 + r] = partial[mt][r];
    }
    __syncthreads();

    // ---- wave 0: final logits + chunk-local softmax stats/weights ----
    if (threadIdx.x < 64) {
        const int t = threadIdx.x;
        float lg = 0.f;
        const bool valid = (t < 32) && (l0 + t < len);
        if (t < 32) {
            lg = b2[0];
            #pragma unroll
            for (int w = 0; w < 4; ++w) lg += red[w * 32 + t];
            logits[(size_t)b * L_ + l0 + t] = lg;
        }
        float mv = valid ? lg : -INFINITY;
        #pragma unroll
        for (int off = 32; off > 0; off >>= 1)
            mv = fmaxf(mv, __shfl_xor(mv, off, 64));
        const float wt = valid ? __expf(lg - mv) : 0.f;
        float sv = wt;
        #pragma unroll
        for (int off = 32; off > 0; off >>= 1) sv += __shfl_xor(sv, off, 64);
        if (t < 32) wbuf[t] = wt;
        if (t == 0) {
            float2 o; o.x = mv; o.y = sv;
            stats_c[(size_t)b * NCH + blockIdx.x] = o;
        }
    }
    __syncthreads();

    // ---- fused context partial: cpart[b][chunk][f] = sum_l w_l*ts[b,l,f] ----
    // ts rows were just staged -> L2-hot; fp32 keeps full context precision.
    const int lend = min(len - l0, TL);
    const float* tsbase = ts + ((size_t)b * L_ + l0) * FT_ + 2 * threadIdx.x;
    float cx = 0.f, cy = 0.f;
    for (int l = 0; l < lend; ++l) {
        const float wl = wbuf[l];
        const float2 v = *(const float2*)(tsbase + (size_t)l * FT_);
        cx += wl * v.x; cy += wl * v.y;
    }
    float2 o; o.x = cx; o.y = cy;
    *(float2*)(cpart + ((size_t)b * NCH + blockIdx.x) * FT_ + 2 * threadIdx.x) = o;
}

// ---------------------------------------------------------------------------
// Kernel 3 (finalize, one block per b, 512 thr = 8 waves):
//   A) global softmax stats from <=128 chunk stats: m = max m_c,
//      tot = sum s_c*exp(m_c-m), inv = 1/tot; chunk scales cached in LDS.
//   B) attn[l] = exp(logit-m)*inv for l<len else 0 (all L written).
//   C) ctx[f]  = inv * sum_c scale_c * cpart[b][c][f].
// Only chunks c < ceil(len/TL) are read (others were never written -- ws is
// re-poisoned between runs).
// ---------------------------------------------------------------------------
__global__ __launch_bounds__(512) void finalize_kernel(
        const float* __restrict__ logits, const float2* __restrict__ stats_c,
        const float* __restrict__ cpart, const int* __restrict__ text_length,
        float* __restrict__ ctx, float* __restrict__ attn_out) {
    const int b   = blockIdx.x;
    const int len = text_length[b];
    const int nv  = (len + TL - 1) / TL;          // valid chunks, 1..128
    const int t   = threadIdx.x;
    __shared__ float sm[NCH];                     // exp(m_c - m)
    __shared__ float redm[8];
    __shared__ float reds[8];

    float2 st; st.x = 0.f; st.y = 0.f;
    float mloc = -INFINITY;
    if (t < nv) { st = stats_c[(size_t)b * NCH + t]; mloc = st.x; }
    float v = mloc;
    #pragma unroll
    for (int off = 32; off > 0; off >>= 1) v = fmaxf(v, __shfl_xor(v, off, 64));
    if ((t & 63) == 0) redm[t >> 6] = v;
    __syncthreads();
    float m = redm[0];
    #pragma unroll
    for (int w = 1; w < 8; ++w) m = fmaxf(m, redm[w]);

    float sume = 0.f;
    if (t < nv) {
        const float sc = __expf(st.x - m);
        sm[t] = sc;
        sume = st.y * sc;
    }
    float sv = sume;
    #pragma unroll
    for (int off = 32; off > 0; off >>= 1) sv += __shfl_xor(sv, off, 64);
    if ((t & 63) == 0) reds[t >> 6] = sv;
    __syncthreads();
    float tot = 0.f;
    #pragma unroll
    for (int w = 0; w < 8; ++w) tot += reds[w];
    const float inv = 1.f / tot;

    // ---- attention output (every slot written; masked -> 0) ----
    const float* lgrow = logits + (size_t)b * L_;
    float* arow = attn_out + (size_t)b * L_;
    #pragma unroll
    for (int i = 0; i < L_ / 512; ++i) {
        const int l = i * 512 + t;
        float a = 0.f;
        if (l < len) a = __expf(lgrow[l] - m) * inv;
        arow[l] = a;
    }

    // ---- context reduce across chunks with exact rescale ----
    const float* cp = cpart + (size_t)b * NCH * FT_ + t;   // thread t <-> feature f=t
    float c = 0.f;
    for (int ch = 0; ch < nv; ++ch) c += sm[ch] * cp[(size_t)ch * FT_];
    ctx[(size_t)b * FT_ + t] = c * inv;
}

// ---------------------------------------------------------------------------
extern "C" void kernel_launch(void* const* d_in, const int* in_sizes, int n_in,
                              void* d_out, int out_size, void* d_ws, size_t ws_size,
                              hipStream_t stream) {
    const float* ts       = (const float*)d_in[0];  // [B,L,FT]
    const float* summary  = (const float*)d_in[1];  // [B,FS]
    const float* coverage = (const float*)d_in[2];  // [B,1,L]
    const float* W1       = (const float*)d_in[3];  // [H,C]
    const float* b1       = (const float*)d_in[4];  // [H]
    const float* W2       = (const float*)d_in[5];  // [1,H]
    const float* b2       = (const float*)d_in[6];  // [1]
    const int*   text_len = (const int*)d_in[7];    // [B]

    float* ctx_out  = (float*)d_out;                // [B,FT]
    float* attn_out = (float*)d_out + B_ * FT_;     // [B,1,L]

    // Workspace layout (bytes, 16B aligned)
    char* ws = (char*)d_ws;
    short*  fragB   = (short*)(ws);                 // 512 KB  @ 0
    float*  w1c     = (float*)(ws + 524288);        // 2 KB
    float*  sconst  = (float*)(ws + 526336);        // 64 KB
    float*  logits  = (float*)(ws + 591872);        // 512 KB
    float2* stats_c = (float2*)(ws + 1116160);      // 32 KB  (B*NCH float2)
    float*  cpart   = (float*)(ws + 1148928);       // 8 MB   (B*NCH*FT)

    prep_kernel<<<128 + 4096, 256, 0, stream>>>(W1, summary, b1, fragB, w1c, sconst);
    logits_ctx_kernel<<<dim3(NCH, B_), 256, 0, stream>>>(
        ts, coverage, text_len, fragB, w1c, sconst, W2, b2, logits, stats_c, cpart);
    finalize_kernel<<<B_, 512, 0, stream>>>(
        logits, stats_c, cpart, text_len, ctx_out, attn_out);
}